// Round 2
// baseline (1047.359 us; speedup 1.0000x reference)
//
#include <hip/hip_runtime.h>
#include <cmath>

typedef __attribute__((ext_vector_type(8))) short short8;
typedef __attribute__((ext_vector_type(4))) float floatx4;

#define N_G 50000
#define E_G 800000
#define N_S 10000
#define E_S 160000
#define BATCH 8

__device__ __forceinline__ short f2b(float f) {
    unsigned u = __builtin_bit_cast(unsigned, f);
    u += 0x7FFF + ((u >> 16) & 1);   // round-to-nearest-even
    return (short)(u >> 16);
}

// ---------------- CSR build ----------------
__global__ void deg_kernel(const int* __restrict__ dst, int E, int* __restrict__ deg) {
    int t = blockIdx.x * blockDim.x + threadIdx.x;
    if (t < E) atomicAdd(&deg[dst[t]], 1);
}

__global__ void scan_kernel(const int* __restrict__ deg, int n,
                            int* __restrict__ ptr, int* __restrict__ cursor) {
    __shared__ int sums[1024];
    int t = threadIdx.x;
    int per = (n + 1023) >> 10;
    int i0 = t * per;
    int i1 = min(n, i0 + per);
    int s = 0;
    for (int i = i0; i < i1; ++i) s += deg[i];
    sums[t] = s;
    __syncthreads();
    for (int off = 1; off < 1024; off <<= 1) {
        int v = (t >= off) ? sums[t - off] : 0;
        __syncthreads();
        sums[t] += v;
        __syncthreads();
    }
    int run = sums[t] - s;
    for (int i = i0; i < i1; ++i) {
        ptr[i] = run; cursor[i] = run; run += deg[i];
    }
    if (t == 1023) ptr[n] = sums[1023];
}

__global__ void fill_kernel(const int* __restrict__ src, const int* __restrict__ dst, int E,
                            int* __restrict__ cursor, int* __restrict__ csr) {
    int t = blockIdx.x * blockDim.x + threadIdx.x;
    if (t < E) {
        int slot = atomicAdd(&cursor[dst[t]], 1);
        csr[slot] = src[t];
    }
}

// ---------------- weight fp32 -> bf16 pre-conversion ----------------
struct WcvtArgs { const float* src[12]; short* dst[12]; int sz[12]; };
__global__ void wcvt_kernel(WcvtArgs a, int total) {
    int t = blockIdx.x * blockDim.x + threadIdx.x;
    if (t >= total) return;
    int off = t, i = 0;
    while (i < 11 && off >= a.sz[i]) { off -= a.sz[i]; ++i; }
    a.dst[i][off] = f2b(a.src[i][off]);
}

// ---------------- edge aggregation (fp32 gather over CSR) ----------------
// thread = (node, 4-float chunk); a node's lanes read contiguous 16B chunks
template<int C>
__global__ void agg_kernel(const float* __restrict__ x, const int* __restrict__ ptr,
                           const int* __restrict__ csr, int n, float* __restrict__ out) {
    constexpr int C4 = C / 4;
    int t = blockIdx.x * blockDim.x + threadIdx.x;
    if (t >= n * C4) return;
    int node = t / C4;
    int ch   = t % C4;
    int e0 = ptr[node], e1 = ptr[node + 1];
    floatx4 acc = {0.f, 0.f, 0.f, 0.f};
    for (int e = e0; e < e1; ++e) {
        int s = csr[e];
        floatx4 v = *(const floatx4*)(x + (size_t)s * C + ch * 4);
        acc += v;
    }
    *(floatx4*)(out + (size_t)node * C + ch * 4) = acc;
}

// ---------------- fused dual-GEMM + bias + ELU via bf16 MFMA ----------------
// out[n][o] = elu( sum_c agg[n][c]*Wr[o][c] + sum_c x[n][c]*Wn[o][c] + b[o] )
template<int CIN, int COUT>
__global__ __launch_bounds__(256) void gemm_elu_kernel(
        const float* __restrict__ A1, const float* __restrict__ A2,
        const short* __restrict__ Wr, const short* __restrict__ Wn,
        const float* __restrict__ bias, int N, float* __restrict__ out) {
    constexpr int NK  = CIN / 16;    // mfma K-steps over K = 2*CIN
    constexpr int NOT = COUT / 16;   // o-tiles
    int wave = (blockIdx.x * blockDim.x + threadIdx.x) >> 6;
    int lane = threadIdx.x & 63;
    if (wave * 16 >= N) return;
    int id = lane & 15, quad = lane >> 4;
    int arow = wave * 16 + id;       // A operand: m = lane&15, k = quad*8+j
    short8 a[NK];
    #pragma unroll
    for (int t = 0; t < NK; ++t) {
        int kk = t * 32 + quad * 8;
        const float* p = (kk < CIN) ? (A1 + (size_t)arow * CIN + kk)
                                    : (A2 + (size_t)arow * CIN + (kk - CIN));
        floatx4 u0 = *(const floatx4*)p;
        floatx4 u1 = *(const floatx4*)(p + 4);
        short8 av;
        av[0] = f2b(u0[0]); av[1] = f2b(u0[1]); av[2] = f2b(u0[2]); av[3] = f2b(u0[3]);
        av[4] = f2b(u1[0]); av[5] = f2b(u1[1]); av[6] = f2b(u1[2]); av[7] = f2b(u1[3]);
        a[t] = av;
    }
    for (int ot = 0; ot < NOT; ++ot) {
        int o = ot * 16 + id;        // B operand: n = lane&15, k = quad*8+j
        floatx4 acc = {0.f, 0.f, 0.f, 0.f};
        #pragma unroll
        for (int t = 0; t < NK; ++t) {
            int kk = t * 32 + quad * 8;
            const short* wp = (kk < CIN) ? (Wr + (size_t)o * CIN + kk)
                                         : (Wn + (size_t)o * CIN + (kk - CIN));
            short8 b = *(const short8*)wp;
            acc = __builtin_amdgcn_mfma_f32_16x16x32_bf16(a[t], b, acc, 0, 0, 0);
        }
        float bv = bias[o];
        #pragma unroll
        for (int r = 0; r < 4; ++r) {
            int nrow = wave * 16 + quad * 4 + r;   // C/D: col=lane&15, row=quad*4+reg
            float v = acc[r] + bv;
            v = (v > 0.f) ? v : (expf(v) - 1.f);
            out[(size_t)nrow * COUT + o] = v;
        }
    }
}

// ---------------- batch boundaries (batch sorted) ----------------
__global__ void bounds_kernel(const int* __restrict__ batch, int n, int* __restrict__ starts) {
    int b = threadIdx.x;
    if (b > BATCH) return;
    if (b == BATCH) { starts[BATCH] = n; return; }
    int lo = 0, hi = n;
    while (lo < hi) { int mid = (lo + hi) >> 1; if (batch[mid] < b) lo = mid + 1; else hi = mid; }
    starts[b] = lo;
}

// ---------------- pooled sum per batch (192 feats) ----------------
__global__ void pool_kernel(const float* __restrict__ h, const int* __restrict__ starts,
                            float* __restrict__ pooled) {
    int b = blockIdx.y;
    int s0 = starts[b], s1 = starts[b + 1];
    int len = s1 - s0;
    int per = (len + gridDim.x - 1) / gridDim.x;
    int ns = s0 + blockIdx.x * per;
    int ne = min(s1, ns + per);
    int f = threadIdx.x;   // 192 threads
    float acc = 0.f;
    for (int i = ns; i < ne; ++i) acc += h[(size_t)i * 192 + f];
    if (ne > ns) atomicAdd(&pooled[b * 192 + f], acc);
}

// ---------------- build MLP input [8,448] ----------------
__global__ void build_in_kernel(const float* __restrict__ pooled_g, const float* __restrict__ pooled_s,
                                const int* __restrict__ starts_g, const int* __restrict__ starts_s,
                                const float* __restrict__ point, float* __restrict__ mlp_in) {
    int t = blockIdx.x * blockDim.x + threadIdx.x;
    if (t >= BATCH * 448) return;
    int b = t / 448, j = t % 448;
    float v;
    if (j < 192) {
        int c = starts_g[b + 1] - starts_g[b];
        v = pooled_g[b * 192 + j] / (float)max(c, 1);
    } else if (j < 384) {
        int c = starts_s[b + 1] - starts_s[b];
        v = pooled_s[b * 192 + (j - 192)] / (float)max(c, 1);
    } else {
        v = point[b * 64 + (j - 384)];
    }
    mlp_in[t] = v;
}

// ---------------- dense (tiny MLP, fp32) ----------------
__global__ void dense_kernel(const float* __restrict__ in, const float* __restrict__ W,
                             const float* __restrict__ bias, float* __restrict__ out,
                             int Brows, int I, int O, int relu) {
    int t = blockIdx.x * blockDim.x + threadIdx.x;
    if (t >= Brows * O) return;
    int b = t / O, o = t % O;
    float acc = 0.f;
    for (int i = 0; i < I; i += 4) {
        floatx4 av = *(const floatx4*)(in + (size_t)b * I + i);
        floatx4 wv = *(const floatx4*)(W + (size_t)o * I + i);
        acc += av[0]*wv[0] + av[1]*wv[1] + av[2]*wv[2] + av[3]*wv[3];
    }
    acc += bias[o];
    if (relu) acc = fmaxf(acc, 0.f);
    out[t] = acc;
}

extern "C" void kernel_launch(void* const* d_in, const int* in_sizes, int n_in,
                              void* d_out, int out_size, void* d_ws, size_t ws_size,
                              hipStream_t stream) {
    const float* graph_x = (const float*)d_in[0];
    const float* sub_x   = (const float*)d_in[1];
    const float* point   = (const float*)d_in[2];
    const int*   g_ei    = (const int*)d_in[3];
    const int*   g_batch = (const int*)d_in[4];
    const int*   s_ei    = (const int*)d_in[5];
    const int*   s_batch = (const int*)d_in[6];
    const float* gB1=(const float*)d_in[9],  *gB2=(const float*)d_in[12], *gB3=(const float*)d_in[15];
    const float* sB1=(const float*)d_in[18], *sB2=(const float*)d_in[21], *sB3=(const float*)d_in[24];
    const float* l1W=(const float*)d_in[25], *l1b=(const float*)d_in[26];
    const float* l2W=(const float*)d_in[27], *l2b=(const float*)d_in[28];
    const float* l3W=(const float*)d_in[29], *l3b=(const float*)d_in[30];

    char* ws = (char*)d_ws;
    size_t off = 0;
    auto alloc = [&](size_t bytes) -> char* {
        char* p = ws + off;
        off = (off + bytes + 255) & ~(size_t)255;
        return p;
    };
    int* deg_g = (int*)alloc((size_t)N_G * 4);
    int* ptr_g = (int*)alloc((size_t)(N_G + 1) * 4);
    int* cur_g = (int*)alloc((size_t)N_G * 4);
    int* csr_g = (int*)alloc((size_t)E_G * 4);
    int* deg_s = (int*)alloc((size_t)N_S * 4);
    int* ptr_s = (int*)alloc((size_t)(N_S + 1) * 4);
    int* cur_s = (int*)alloc((size_t)N_S * 4);
    int* csr_s = (int*)alloc((size_t)E_S * 4);

    // bf16 weight slab: 12 conv weights
    const int wsz[12] = {128*64,128*64, 256*128,256*128, 192*256,192*256,
                         128*64,128*64, 256*128,256*128, 192*256,192*256};
    const int widx[12] = {7,8, 10,11, 13,14, 16,17, 19,20, 22,23};
    int wtotal = 0; for (int i = 0; i < 12; ++i) wtotal += wsz[i];
    short* wbf = (short*)alloc((size_t)wtotal * 2);
    short* wptr[12]; { int o2 = 0; for (int i = 0; i < 12; ++i) { wptr[i] = wbf + o2; o2 += wsz[i]; } }

    // big slabs (shared between g and s branches; g is pooled before s starts)
    float* slabA = (float*)alloc((size_t)N_G * 256 * 4);  // agg buffer
    float* slabB = (float*)alloc((size_t)N_G * 256 * 4);  // h2
    float* slabC = (float*)alloc((size_t)N_G * 192 * 4);  // h1 (first part) then h3

    float* pooled_g = (float*)alloc(BATCH * 192 * 4);
    float* pooled_s = (float*)alloc(BATCH * 192 * 4);
    int* starts_g = (int*)alloc((BATCH + 1) * 4);
    int* starts_s = (int*)alloc((BATCH + 1) * 4);
    float* mlp_in = (float*)alloc(BATCH * 448 * 4);
    float* mlp_h1 = (float*)alloc(BATCH * 600 * 4);
    float* mlp_h2 = (float*)alloc(BATCH * 256 * 4);

    hipMemsetAsync(deg_g, 0, (size_t)N_G * 4, stream);
    hipMemsetAsync(deg_s, 0, (size_t)N_S * 4, stream);
    hipMemsetAsync(pooled_g, 0, BATCH * 192 * 4, stream);
    hipMemsetAsync(pooled_s, 0, BATCH * 192 * 4, stream);

    // weight conversion
    WcvtArgs wa;
    for (int i = 0; i < 12; ++i) { wa.src[i] = (const float*)d_in[widx[i]]; wa.dst[i] = wptr[i]; wa.sz[i] = wsz[i]; }
    wcvt_kernel<<<(wtotal + 255) / 256, 256, 0, stream>>>(wa, wtotal);

    // CSR build (src = ei[0..E), dst = ei[E..2E))
    deg_kernel<<<(E_G + 255) / 256, 256, 0, stream>>>(g_ei + E_G, E_G, deg_g);
    scan_kernel<<<1, 1024, 0, stream>>>(deg_g, N_G, ptr_g, cur_g);
    fill_kernel<<<(E_G + 255) / 256, 256, 0, stream>>>(g_ei, g_ei + E_G, E_G, cur_g, csr_g);
    deg_kernel<<<(E_S + 255) / 256, 256, 0, stream>>>(s_ei + E_S, E_S, deg_s);
    scan_kernel<<<1, 1024, 0, stream>>>(deg_s, N_S, ptr_s, cur_s);
    fill_kernel<<<(E_S + 255) / 256, 256, 0, stream>>>(s_ei, s_ei + E_S, E_S, cur_s, csr_s);

    bounds_kernel<<<1, 64, 0, stream>>>(g_batch, N_G, starts_g);
    bounds_kernel<<<1, 64, 0, stream>>>(s_batch, N_S, starts_s);

    // ---- graph branch ----
    float* agg_g = slabA;
    float* h1_g  = slabC;          // 50000*128
    float* h2_g  = slabB;          // 50000*256
    float* h3_g  = slabC;          // 50000*192 (h1 dead by then)
    agg_kernel<64><<<(N_G * 16 + 255) / 256, 256, 0, stream>>>(graph_x, ptr_g, csr_g, N_G, agg_g);
    gemm_elu_kernel<64, 128><<<((N_G / 16) + 3) / 4, 256, 0, stream>>>(agg_g, graph_x, wptr[0], wptr[1], gB1, N_G, h1_g);
    agg_kernel<128><<<(N_G * 32 + 255) / 256, 256, 0, stream>>>(h1_g, ptr_g, csr_g, N_G, agg_g);
    gemm_elu_kernel<128, 256><<<((N_G / 16) + 3) / 4, 256, 0, stream>>>(agg_g, h1_g, wptr[2], wptr[3], gB2, N_G, h2_g);
    agg_kernel<256><<<(N_G * 64 + 255) / 256, 256, 0, stream>>>(h2_g, ptr_g, csr_g, N_G, agg_g);
    gemm_elu_kernel<256, 192><<<((N_G / 16) + 3) / 4, 256, 0, stream>>>(agg_g, h2_g, wptr[4], wptr[5], gB3, N_G, h3_g);
    pool_kernel<<<dim3(32, BATCH), 192, 0, stream>>>(h3_g, starts_g, pooled_g);

    // ---- subgraph branch (reuses slabs; g-branch data is dead) ----
    float* agg_s = slabA;
    float* h1_s  = slabC;
    float* h2_s  = slabB;
    float* h3_s  = slabC;
    agg_kernel<64><<<(N_S * 16 + 255) / 256, 256, 0, stream>>>(sub_x, ptr_s, csr_s, N_S, agg_s);
    gemm_elu_kernel<64, 128><<<((N_S / 16) + 3) / 4, 256, 0, stream>>>(agg_s, sub_x, wptr[6], wptr[7], sB1, N_S, h1_s);
    agg_kernel<128><<<(N_S * 32 + 255) / 256, 256, 0, stream>>>(h1_s, ptr_s, csr_s, N_S, agg_s);
    gemm_elu_kernel<128, 256><<<((N_S / 16) + 3) / 4, 256, 0, stream>>>(agg_s, h1_s, wptr[8], wptr[9], sB2, N_S, h2_s);
    agg_kernel<256><<<(N_S * 64 + 255) / 256, 256, 0, stream>>>(h2_s, ptr_s, csr_s, N_S, agg_s);
    gemm_elu_kernel<256, 192><<<((N_S / 16) + 3) / 4, 256, 0, stream>>>(agg_s, h2_s, wptr[10], wptr[11], sB3, N_S, h3_s);
    pool_kernel<<<dim3(32, BATCH), 192, 0, stream>>>(h3_s, starts_s, pooled_s);

    // ---- head MLP ----
    build_in_kernel<<<(BATCH * 448 + 255) / 256, 256, 0, stream>>>(pooled_g, pooled_s, starts_g, starts_s, point, mlp_in);
    dense_kernel<<<(BATCH * 600 + 255) / 256, 256, 0, stream>>>(mlp_in, l1W, l1b, mlp_h1, BATCH, 448, 600, 1);
    dense_kernel<<<(BATCH * 256 + 255) / 256, 256, 0, stream>>>(mlp_h1, l2W, l2b, mlp_h2, BATCH, 600, 256, 1);
    dense_kernel<<<(BATCH * 64 + 255) / 256, 256, 0, stream>>>(mlp_h2, l3W, l3b, (float*)d_out, BATCH, 256, 64, 0);
}